// Round 1
// baseline (1922.448 us; speedup 1.0000x reference)
//
#include <hip/hip_runtime.h>

#define LRC 0.01f
#define LSEQ 4096
#define HIDDIM 128

// 64-lane sum reduction, result broadcast to all lanes.
// xor butterfly: stages 1..16 via ds_swizzle (within 32-lane halves),
// stage 32 via __shfl_xor (ds_bpermute).
__device__ __forceinline__ float red64(float x) {
  x += __int_as_float(__builtin_amdgcn_ds_swizzle(__float_as_int(x), 0x041F)); // xor 1
  x += __int_as_float(__builtin_amdgcn_ds_swizzle(__float_as_int(x), 0x081F)); // xor 2
  x += __int_as_float(__builtin_amdgcn_ds_swizzle(__float_as_int(x), 0x101F)); // xor 4
  x += __int_as_float(__builtin_amdgcn_ds_swizzle(__float_as_int(x), 0x201F)); // xor 8
  x += __int_as_float(__builtin_amdgcn_ds_swizzle(__float_as_int(x), 0x401F)); // xor 16
  x += __shfl_xor(x, 32, 64);                                                  // xor 32
  return x;
}

__global__ __launch_bounds__(64) void ttt_kernel(
    const float* __restrict__ h, const float* __restrict__ W1,
    const float* __restrict__ b1, const float* __restrict__ W2,
    const float* __restrict__ b2, float* __restrict__ out) {
  const int b = blockIdx.x;
  const int lane = threadIdx.x;      // 0..63
  const int d0 = lane * 2;           // this lane owns hidden dims d0, d0+1
  const float* __restrict__ hb = h + (size_t)b * (LSEQ * HIDDIM);

  // ---- load weight state into registers ----
  float2 w1v[8];   // w1v[i] = (W1[i][d0], W1[i][d0+1])
  float2 w2v[8];   // w2v[i] = (W2[d0][i], W2[d0+1][i])
  float b1r[8];    // b1 replicated across lanes
#pragma unroll
  for (int i = 0; i < 8; ++i) {
    w1v[i] = *reinterpret_cast<const float2*>(W1 + i * HIDDIM + d0);
    w2v[i].x = W2[(size_t)d0 * 8 + i];
    w2v[i].y = W2[(size_t)(d0 + 1) * 8 + i];
    b1r[i] = b1[i];
  }
  float2 b2v = *reinterpret_cast<const float2*>(b2 + d0);

  const float cneg = -(LRC * 2.0f / (float)HIDDIM);  // -lr * dMSE/dpred scale

  // ---- double-buffered k/v prefetch (2 steps ahead) ----
  float2 kA = *reinterpret_cast<const float2*>(hb + 0 * HIDDIM + d0);
  float2 vA = *reinterpret_cast<const float2*>(hb + 1 * HIDDIM + d0);
  float2 kB = *reinterpret_cast<const float2*>(hb + 2 * HIDDIM + d0);
  float2 vB = *reinterpret_cast<const float2*>(hb + 3 * HIDDIM + d0);
  const float* pf = hb + 4 * HIDDIM + d0;  // next row-pair to prefetch

  float a[8], r[8];

  // One SGD step. gl = -lr * (2/H) * (pred - v); all updates via += (signs folded).
  auto STEP = [&](float2 k, float2 v) {
    float pa[8];
#pragma unroll
    for (int i = 0; i < 8; ++i) pa[i] = fmaf(w1v[i].x, k.x, w1v[i].y * k.y);
#pragma unroll
    for (int i = 0; i < 8; ++i) {
      a[i] = red64(pa[i]) + b1r[i];
      r[i] = fmaxf(a[i], 0.0f);
    }
    float2 pred = b2v;
#pragma unroll
    for (int i = 0; i < 8; ++i) {
      pred.x = fmaf(w2v[i].x, r[i], pred.x);
      pred.y = fmaf(w2v[i].y, r[i], pred.y);
    }
    float2 gl;
    gl.x = (pred.x - v.x) * cneg;
    gl.y = (pred.y - v.y) * cneg;
    // da partials from OLD w2 (before the w2 update below)
    float dp[8];
#pragma unroll
    for (int i = 0; i < 8; ++i) dp[i] = fmaf(w2v[i].x, gl.x, w2v[i].y * gl.y);
    // w2, b2 updates: w2 += gl * r  (== w2 - lr*g*r)
#pragma unroll
    for (int i = 0; i < 8; ++i) {
      w2v[i].x = fmaf(gl.x, r[i], w2v[i].x);
      w2v[i].y = fmaf(gl.y, r[i], w2v[i].y);
    }
    b2v.x += gl.x;
    b2v.y += gl.y;
    // reduce da, mask by (a > 0), update w1/b1
#pragma unroll
    for (int i = 0; i < 8; ++i) {
      float da = red64(dp[i]);
      da = (a[i] > 0.0f) ? da : 0.0f;  // == -lr * da_ref
      w1v[i].x = fmaf(da, k.x, w1v[i].x);
      w1v[i].y = fmaf(da, k.y, w1v[i].y);
      b1r[i] += da;
    }
  };

  // 2047 steps = 1023 * 2 + 1.  Manual 2x unroll, named A/B buffers
  // (no runtime-indexed arrays -> no scratch).
  for (int it = 0; it < 1023; ++it) {
    {
      float2 k = kA, v = vA;
      kA = *reinterpret_cast<const float2*>(pf);               // rows 4it+4, +5
      vA = *reinterpret_cast<const float2*>(pf + HIDDIM);
      STEP(k, v);                                              // s = 2it
    }
    {
      float2 k = kB, v = vB;
      kB = *reinterpret_cast<const float2*>(pf + 2 * HIDDIM);  // rows 4it+6, +7 (<=4095)
      vB = *reinterpret_cast<const float2*>(pf + 3 * HIDDIM);
      STEP(k, v);                                              // s = 2it+1
    }
    pf += 4 * HIDDIM;
  }
  STEP(kA, vA);  // s = 2046 (rows 4092, 4093)

  // ---- final prediction with x = h[b, L-1] ----
  float2 x = *reinterpret_cast<const float2*>(hb + (size_t)(LSEQ - 1) * HIDDIM + d0);
  float pa[8];
#pragma unroll
  for (int i = 0; i < 8; ++i) pa[i] = fmaf(w1v[i].x, x.x, w1v[i].y * x.y);
#pragma unroll
  for (int i = 0; i < 8; ++i) {
    a[i] = red64(pa[i]) + b1r[i];
    r[i] = fmaxf(a[i], 0.0f);
  }
  float2 o = b2v;
#pragma unroll
  for (int i = 0; i < 8; ++i) {
    o.x = fmaf(w2v[i].x, r[i], o.x);
    o.y = fmaf(w2v[i].y, r[i], o.y);
  }
  *reinterpret_cast<float2*>(out + (size_t)b * HIDDIM + d0) = o;
}

extern "C" void kernel_launch(void* const* d_in, const int* in_sizes, int n_in,
                              void* d_out, int out_size, void* d_ws, size_t ws_size,
                              hipStream_t stream) {
  const float* h  = (const float*)d_in[0];
  const float* W1 = (const float*)d_in[1];
  const float* b1 = (const float*)d_in[2];
  const float* W2 = (const float*)d_in[3];
  const float* b2 = (const float*)d_in[4];
  float* out = (float*)d_out;
  ttt_kernel<<<256, 64, 0, stream>>>(h, W1, b1, W2, b2, out);
}

// Round 2
// 1075.916 us; speedup vs baseline: 1.7868x; 1.7868x over previous
//
#include <hip/hip_runtime.h>

#define LRC 0.01f
#define LSEQ 4096
#define HIDDIM 128

// Fused DPP add: x += dpp_move(x, CTRL), 0-filled for invalid source lanes.
// GCNDPPCombine folds the v_mov_b32_dpp into v_add_f32_dpp; hazards handled
// by the compiler (intrinsic path, not inline asm).
#define DPP_ADD(x, ctrl)                                                     \
  x += __int_as_float(__builtin_amdgcn_update_dpp(                           \
      0, __float_as_int(x), (ctrl), 0xf, 0xf, true))

// 64-lane sum -> wave-uniform scalar (SGPR via readlane).
// row_shr 1,2,4,8 gives per-row prefix sums (lane15/31/47/63 = row totals),
// row_bcast:15 then row_bcast:31 accumulate rows so lane 63 holds the total.
__device__ __forceinline__ float red64(float x) {
  DPP_ADD(x, 0x111);  // row_shr:1
  DPP_ADD(x, 0x112);  // row_shr:2
  DPP_ADD(x, 0x114);  // row_shr:4
  DPP_ADD(x, 0x118);  // row_shr:8
  DPP_ADD(x, 0x142);  // row_bcast:15
  DPP_ADD(x, 0x143);  // row_bcast:31
  return __int_as_float(__builtin_amdgcn_readlane(__float_as_int(x), 63));
}

__global__ __launch_bounds__(64) void ttt_kernel(
    const float* __restrict__ h, const float* __restrict__ W1,
    const float* __restrict__ b1, const float* __restrict__ W2,
    const float* __restrict__ b2, float* __restrict__ out) {
  const int b = blockIdx.x;
  const int lane = threadIdx.x;      // 0..63
  const int d0 = lane * 2;           // this lane owns hidden dims d0, d0+1
  const float* __restrict__ hb = h + (size_t)b * (LSEQ * HIDDIM);

  // ---- load weight state into registers ----
  float2 w1v[8];   // w1v[i] = (W1[i][d0], W1[i][d0+1])
  float2 w2v[8];   // w2v[i] = (W2[d0][i], W2[d0+1][i])
  float b1r[8];    // b1 replicated across lanes
#pragma unroll
  for (int i = 0; i < 8; ++i) {
    w1v[i] = *reinterpret_cast<const float2*>(W1 + i * HIDDIM + d0);
    w2v[i].x = W2[(size_t)d0 * 8 + i];
    w2v[i].y = W2[(size_t)(d0 + 1) * 8 + i];
    b1r[i] = b1[i];
  }
  float2 b2v = *reinterpret_cast<const float2*>(b2 + d0);

  const float cneg = -(LRC * 2.0f / (float)HIDDIM);  // -lr * dMSE/dpred scale

  // ---- double-buffered k/v prefetch (2 steps ahead) ----
  float2 kA = *reinterpret_cast<const float2*>(hb + 0 * HIDDIM + d0);
  float2 vA = *reinterpret_cast<const float2*>(hb + 1 * HIDDIM + d0);
  float2 kB = *reinterpret_cast<const float2*>(hb + 2 * HIDDIM + d0);
  float2 vB = *reinterpret_cast<const float2*>(hb + 3 * HIDDIM + d0);
  const float* pf = hb + 4 * HIDDIM + d0;  // next row-pair to prefetch

  float a[8], r[8];

  // One SGD step. gl = -lr * (2/H) * (pred - v); all updates via += (signs folded).
  auto STEP = [&](float2 k, float2 v) {
    float pa[8];
#pragma unroll
    for (int i = 0; i < 8; ++i) pa[i] = fmaf(w1v[i].x, k.x, w1v[i].y * k.y);
#pragma unroll
    for (int i = 0; i < 8; ++i) {
      a[i] = red64(pa[i]) + b1r[i];
      r[i] = fmaxf(a[i], 0.0f);
    }
    // pred: two partial accumulators to halve the dependent FMA chain
    float2 p0 = b2v, p1;
    p1.x = w2v[1].x * r[1];
    p1.y = w2v[1].y * r[1];
    p0.x = fmaf(w2v[0].x, r[0], p0.x);
    p0.y = fmaf(w2v[0].y, r[0], p0.y);
#pragma unroll
    for (int i = 2; i < 8; i += 2) {
      p0.x = fmaf(w2v[i].x, r[i], p0.x);
      p0.y = fmaf(w2v[i].y, r[i], p0.y);
      p1.x = fmaf(w2v[i + 1].x, r[i + 1], p1.x);
      p1.y = fmaf(w2v[i + 1].y, r[i + 1], p1.y);
    }
    float2 pred;
    pred.x = p0.x + p1.x;
    pred.y = p0.y + p1.y;
    float2 gl;
    gl.x = (pred.x - v.x) * cneg;
    gl.y = (pred.y - v.y) * cneg;
    // da partials from OLD w2 (before the w2 update below)
    float dp[8];
#pragma unroll
    for (int i = 0; i < 8; ++i) dp[i] = fmaf(w2v[i].x, gl.x, w2v[i].y * gl.y);
    // w2, b2 updates: w2 += gl * r  (== w2 - lr*g*r)
#pragma unroll
    for (int i = 0; i < 8; ++i) {
      w2v[i].x = fmaf(gl.x, r[i], w2v[i].x);
      w2v[i].y = fmaf(gl.y, r[i], w2v[i].y);
    }
    b2v.x += gl.x;
    b2v.y += gl.y;
    // reduce da, mask by (a > 0), update w1/b1
#pragma unroll
    for (int i = 0; i < 8; ++i) {
      float da = red64(dp[i]);
      da = (a[i] > 0.0f) ? da : 0.0f;  // == -lr * da_ref
      w1v[i].x = fmaf(da, k.x, w1v[i].x);
      w1v[i].y = fmaf(da, k.y, w1v[i].y);
      b1r[i] += da;
    }
  };

  // 2047 steps = 1023 * 2 + 1.  Manual 2x unroll, named A/B buffers
  // (no runtime-indexed arrays -> no scratch).
  for (int it = 0; it < 1023; ++it) {
    {
      float2 k = kA, v = vA;
      kA = *reinterpret_cast<const float2*>(pf);               // rows 4it+4, +5
      vA = *reinterpret_cast<const float2*>(pf + HIDDIM);
      STEP(k, v);                                              // s = 2it
    }
    {
      float2 k = kB, v = vB;
      kB = *reinterpret_cast<const float2*>(pf + 2 * HIDDIM);  // rows 4it+6, +7 (<=4095)
      vB = *reinterpret_cast<const float2*>(pf + 3 * HIDDIM);
      STEP(k, v);                                              // s = 2it+1
    }
    pf += 4 * HIDDIM;
  }
  STEP(kA, vA);  // s = 2046 (rows 4092, 4093)

  // ---- final prediction with x = h[b, L-1] ----
  float2 x = *reinterpret_cast<const float2*>(hb + (size_t)(LSEQ - 1) * HIDDIM + d0);
  float pa[8];
#pragma unroll
  for (int i = 0; i < 8; ++i) pa[i] = fmaf(w1v[i].x, x.x, w1v[i].y * x.y);
#pragma unroll
  for (int i = 0; i < 8; ++i) {
    a[i] = red64(pa[i]) + b1r[i];
    r[i] = fmaxf(a[i], 0.0f);
  }
  float2 o = b2v;
#pragma unroll
  for (int i = 0; i < 8; ++i) {
    o.x = fmaf(w2v[i].x, r[i], o.x);
    o.y = fmaf(w2v[i].y, r[i], o.y);
  }
  *reinterpret_cast<float2*>(out + (size_t)b * HIDDIM + d0) = o;
}

extern "C" void kernel_launch(void* const* d_in, const int* in_sizes, int n_in,
                              void* d_out, int out_size, void* d_ws, size_t ws_size,
                              hipStream_t stream) {
  const float* h  = (const float*)d_in[0];
  const float* W1 = (const float*)d_in[1];
  const float* b1 = (const float*)d_in[2];
  const float* W2 = (const float*)d_in[3];
  const float* b2 = (const float*)d_in[4];
  float* out = (float*)d_out;
  ttt_kernel<<<256, 64, 0, stream>>>(h, W1, b1, W2, b2, out);
}

// Round 3
// 759.983 us; speedup vs baseline: 2.5296x; 1.4157x over previous
//
#include <hip/hip_runtime.h>

#define LRC 0.01f
#define LSEQ 4096
#define HIDDIM 128

typedef unsigned int uint2e __attribute__((ext_vector_type(2)));

// Fused DPP add: x += dpp_move(x, CTRL), 0-fill for invalid lanes.
#define DPP_ADD(x, ctrl)                                                     \
  x += __int_as_float(__builtin_amdgcn_update_dpp(                           \
      0, __float_as_int(x), (ctrl), 0xf, 0xf, true))

// Classic 64-lane sum -> wave-uniform scalar (used for the lone kk value).
__device__ __forceinline__ float red64(float x) {
  DPP_ADD(x, 0x111);  // row_shr:1
  DPP_ADD(x, 0x112);  // row_shr:2
  DPP_ADD(x, 0x114);  // row_shr:4
  DPP_ADD(x, 0x118);  // row_shr:8
  DPP_ADD(x, 0x142);  // row_bcast:15
  DPP_ADD(x, 0x143);  // row_bcast:31
  return __int_as_float(__builtin_amdgcn_readlane(__float_as_int(x), 63));
}

#if __has_builtin(__builtin_amdgcn_permlane32_swap) && \
    __has_builtin(__builtin_amdgcn_permlane16_swap)
// 4 simultaneous 64-lane sums in 14 instrs (3.5/value vs 7):
//   permlane32_swap folds 64->32 for two values at once,
//   permlane16_swap folds 32->16 for all four,
//   4 shared row_shr stages reduce rows [p,u,q,w], readlane 15/31/47/63.
__device__ __forceinline__ void quad_red(float p, float q, float u, float w,
                                         float& rp, float& rq, float& ru,
                                         float& rw) {
  uint2e s1 = __builtin_amdgcn_permlane32_swap(__float_as_uint(p),
                                               __float_as_uint(q), false, false);
  float zpq = __uint_as_float(s1.x) + __uint_as_float(s1.y);
  uint2e s2 = __builtin_amdgcn_permlane32_swap(__float_as_uint(u),
                                               __float_as_uint(w), false, false);
  float zuw = __uint_as_float(s2.x) + __uint_as_float(s2.y);
  uint2e s3 = __builtin_amdgcn_permlane16_swap(__float_as_uint(zpq),
                                               __float_as_uint(zuw), false, false);
  float y = __uint_as_float(s3.x) + __uint_as_float(s3.y);
  DPP_ADD(y, 0x111);
  DPP_ADD(y, 0x112);
  DPP_ADD(y, 0x114);
  DPP_ADD(y, 0x118);
  rp = __int_as_float(__builtin_amdgcn_readlane(__float_as_int(y), 15));
  ru = __int_as_float(__builtin_amdgcn_readlane(__float_as_int(y), 31));
  rq = __int_as_float(__builtin_amdgcn_readlane(__float_as_int(y), 47));
  rw = __int_as_float(__builtin_amdgcn_readlane(__float_as_int(y), 63));
}
#else
__device__ __forceinline__ void quad_red(float p, float q, float u, float w,
                                         float& rp, float& rq, float& ru,
                                         float& rw) {
  rp = red64(p); rq = red64(q); ru = red64(u); rw = red64(w);
}
#endif

__global__ __launch_bounds__(64) void ttt_kernel(
    const float* __restrict__ h, const float* __restrict__ W1,
    const float* __restrict__ b1, const float* __restrict__ W2,
    const float* __restrict__ b2, float* __restrict__ out) {
  const int b = blockIdx.x;
  const int lane = threadIdx.x;  // 0..63
  const int d0 = lane * 2;       // lane owns hidden dims d0, d0+1
  const float* __restrict__ hb = h + (size_t)b * (LSEQ * HIDDIM);

  // ---- weight state in registers ----
  float2 w1v[8];  // (W1[i][d0], W1[i][d0+1])
  float2 w2v[8];  // (W2[d0][i], W2[d0+1][i])
  float b1r[8];   // replicated
#pragma unroll
  for (int i = 0; i < 8; ++i) {
    w1v[i] = *reinterpret_cast<const float2*>(W1 + i * HIDDIM + d0);
    w2v[i].x = W2[(size_t)d0 * 8 + i];
    w2v[i].y = W2[(size_t)(d0 + 1) * 8 + i];
    b1r[i] = b1[i];
  }
  float2 b2v = *reinterpret_cast<const float2*>(b2 + d0);

  const float cneg = -(LRC * 2.0f / (float)HIDDIM);

  // ---- 3-slot k/v rotation, prefetch distance 3 steps ----
  const float* pf = hb + d0;
  float2 kA = *reinterpret_cast<const float2*>(pf + 0 * HIDDIM);
  float2 vA = *reinterpret_cast<const float2*>(pf + 1 * HIDDIM);
  float2 kB = *reinterpret_cast<const float2*>(pf + 2 * HIDDIM);
  float2 vB = *reinterpret_cast<const float2*>(pf + 3 * HIDDIM);
  float2 kC = *reinterpret_cast<const float2*>(pf + 4 * HIDDIM);
  float2 vC = *reinterpret_cast<const float2*>(pf + 5 * HIDDIM);
  pf += 6 * HIDDIM;

  // ---- a(0) = W1 k(0) + b1 ----
  float aIn[8];
  {
    float pa[8];
#pragma unroll
    for (int i = 0; i < 8; ++i) pa[i] = fmaf(w1v[i].x, kA.x, w1v[i].y * kA.y);
    float t0, t1, t2, t3, t4, t5, t6, t7;
    quad_red(pa[0], pa[1], pa[2], pa[3], t0, t1, t2, t3);
    quad_red(pa[4], pa[5], pa[6], pa[7], t4, t5, t6, t7);
    aIn[0] = t0 + b1r[0]; aIn[1] = t1 + b1r[1];
    aIn[2] = t2 + b1r[2]; aIn[3] = t3 + b1r[3];
    aIn[4] = t4 + b1r[4]; aIn[5] = t5 + b1r[5];
    aIn[6] = t6 + b1r[6]; aIn[7] = t7 + b1r[7];
  }

  // One SGD step s. In: a(s) (aIn), k(s), v(s), k(s+1).
  // Out: updated weights and aIn = a(s+1) via rank-1 factorization:
  //   a(s+1) = red(W1(s) k(s+1)) + da(s)*(red(k(s)·k(s+1)) + 1) + b1(s)
  auto STEP = [&](float2 k, float2 v, float2 kn) {
    // relu
    float r_[8];
#pragma unroll
    for (int i = 0; i < 8; ++i) r_[i] = fmaxf(aIn[i], 0.0f);
    // pred = W2 r + b2 (two partial accumulators)
    float2 p0 = b2v, p1;
    p1.x = w2v[1].x * r_[1];
    p1.y = w2v[1].y * r_[1];
    p0.x = fmaf(w2v[0].x, r_[0], p0.x);
    p0.y = fmaf(w2v[0].y, r_[0], p0.y);
#pragma unroll
    for (int i = 2; i < 8; i += 2) {
      p0.x = fmaf(w2v[i].x, r_[i], p0.x);
      p0.y = fmaf(w2v[i].y, r_[i], p0.y);
      p1.x = fmaf(w2v[i + 1].x, r_[i + 1], p1.x);
      p1.y = fmaf(w2v[i + 1].y, r_[i + 1], p1.y);
    }
    float2 gl;
    gl.x = (p0.x + p1.x - v.x) * cneg;
    gl.y = (p0.y + p1.y - v.y) * cneg;
    // da partials from OLD w2 (critical path: reduce first)
    float dp[8];
#pragma unroll
    for (int i = 0; i < 8; ++i) dp[i] = fmaf(w2v[i].x, gl.x, w2v[i].y * gl.y);
    float dr0, dr1, dr2, dr3, dr4, dr5, dr6, dr7;
    quad_red(dp[0], dp[1], dp[2], dp[3], dr0, dr1, dr2, dr3);
    quad_red(dp[4], dp[5], dp[6], dp[7], dr4, dr5, dr6, dr7);
    float dpred[8] = {dr0, dr1, dr2, dr3, dr4, dr5, dr6, dr7};
    // next-step a: partials with OLD w1 and k(s+1), plus kk = k(s)·k(s+1)
    float t1p[8];
#pragma unroll
    for (int i = 0; i < 8; ++i) t1p[i] = fmaf(w1v[i].x, kn.x, w1v[i].y * kn.y);
    float kkp = fmaf(k.x, kn.x, k.y * kn.y);
    float u0, u1, u2, u3, u4, u5, u6, u7;
    quad_red(t1p[0], t1p[1], t1p[2], t1p[3], u0, u1, u2, u3);
    quad_red(t1p[4], t1p[5], t1p[6], t1p[7], u4, u5, u6, u7);
    float t1r[8] = {u0, u1, u2, u3, u4, u5, u6, u7};
    float kkp1 = red64(kkp) + 1.0f;
    // w2 / b2 update
#pragma unroll
    for (int i = 0; i < 8; ++i) {
      w2v[i].x = fmaf(gl.x, r_[i], w2v[i].x);
      w2v[i].y = fmaf(gl.y, r_[i], w2v[i].y);
    }
    b2v.x += gl.x;
    b2v.y += gl.y;
    // da mask, w1 / b1 update, next a
#pragma unroll
    for (int i = 0; i < 8; ++i) {
      float da = (aIn[i] > 0.0f) ? dpred[i] : 0.0f;  // == -lr * da_ref
      float tb = t1r[i] + b1r[i];                     // uses OLD b1
      w1v[i].x = fmaf(da, k.x, w1v[i].x);
      w1v[i].y = fmaf(da, k.y, w1v[i].y);
      b1r[i] += da;
      aIn[i] = fmaf(da, kkp1, tb);                    // a(s+1)
    }
  };

  // steps 0..2042: 681 iterations x 3 (3-slot rotation)
  for (int it = 0; it < 681; ++it) {
    {
      float2 k = kA, v = vA, kn = kB;
      kA = *reinterpret_cast<const float2*>(pf + 0 * HIDDIM);
      vA = *reinterpret_cast<const float2*>(pf + 1 * HIDDIM);
      STEP(k, v, kn);  // s = 3it
    }
    {
      float2 k = kB, v = vB, kn = kC;
      kB = *reinterpret_cast<const float2*>(pf + 2 * HIDDIM);
      vB = *reinterpret_cast<const float2*>(pf + 3 * HIDDIM);
      STEP(k, v, kn);  // s = 3it+1
    }
    {
      float2 k = kC, v = vC, kn = kA;  // kn = freshly loaded k(3it+3)
      kC = *reinterpret_cast<const float2*>(pf + 4 * HIDDIM);
      vC = *reinterpret_cast<const float2*>(pf + 5 * HIDDIM);
      STEP(k, v, kn);  // s = 3it+2
    }
    pf += 6 * HIDDIM;
  }

  // tail: pf at row 4092. steps 2043..2046, then final predict with row 4095.
  float2 kD = *reinterpret_cast<const float2*>(pf + 0 * HIDDIM);  // row 4092
  float2 vD = *reinterpret_cast<const float2*>(pf + 1 * HIDDIM);  // row 4093
  float2 kE = *reinterpret_cast<const float2*>(pf + 2 * HIDDIM);  // row 4094
  float2 xv = *reinterpret_cast<const float2*>(pf + 3 * HIDDIM);  // row 4095
  STEP(kA, vA, kB);  // 2043 (rows 4086/4087)
  STEP(kB, vB, kC);  // 2044
  STEP(kC, vC, kD);  // 2045
  STEP(kD, vD, kE);  // 2046 (kn only feeds a discarded aIn)

  // ---- final prediction with x = h[b, L-1] ----
  float pa[8];
#pragma unroll
  for (int i = 0; i < 8; ++i) pa[i] = fmaf(w1v[i].x, xv.x, w1v[i].y * xv.y);
  float f0, f1, f2, f3, f4, f5, f6, f7;
  quad_red(pa[0], pa[1], pa[2], pa[3], f0, f1, f2, f3);
  quad_red(pa[4], pa[5], pa[6], pa[7], f4, f5, f6, f7);
  float fr[8] = {f0, f1, f2, f3, f4, f5, f6, f7};
  float2 o = b2v;
#pragma unroll
  for (int i = 0; i < 8; ++i) {
    float r = fmaxf(fr[i] + b1r[i], 0.0f);
    o.x = fmaf(w2v[i].x, r, o.x);
    o.y = fmaf(w2v[i].y, r, o.y);
  }
  *reinterpret_cast<float2*>(out + (size_t)b * HIDDIM + d0) = o;
}

extern "C" void kernel_launch(void* const* d_in, const int* in_sizes, int n_in,
                              void* d_out, int out_size, void* d_ws, size_t ws_size,
                              hipStream_t stream) {
  const float* h  = (const float*)d_in[0];
  const float* W1 = (const float*)d_in[1];
  const float* b1 = (const float*)d_in[2];
  const float* W2 = (const float*)d_in[3];
  const float* b2 = (const float*)d_in[4];
  float* out = (float*)d_out;
  ttt_kernel<<<256, 64, 0, stream>>>(h, W1, b1, W2, b2, out);
}